// Round 2
// baseline (239.141 us; speedup 1.0000x reference)
//
#include <hip/hip_runtime.h>
#include <stdint.h>

static constexpr int BB = 32;
static constexpr int TT = 2048;
static constexpr int DD = 512;
static constexpr int IDX_STRIDE = 320;   // >= kmax = ceil(2048*0.15) = 308

// ---------------------------------------------------------------------------
// Kernel 1: per-(b,t) L2 norm -> 32-bit order key.
// One wave per timestep row (512 floats = 2KB). key = bits(norm)+1 if valid,
// 0 if t >= len. Non-negative float bits are monotone, +1 keeps valid > masked.
// ---------------------------------------------------------------------------
__global__ __launch_bounds__(256) void topq_norms(
    const float* __restrict__ H, const int* __restrict__ lengths,
    unsigned int* __restrict__ keys)
{
    const int wave = threadIdx.x >> 6;
    const int lane = threadIdx.x & 63;
    const int row  = (blockIdx.x << 2) + wave;          // b*T + t
    const float4* p = reinterpret_cast<const float4*>(H) + (size_t)row * (DD / 4);
    float4 a = p[lane];        // contiguous 1KB per instruction across the wave
    float4 c = p[lane + 64];
    float s = a.x*a.x + a.y*a.y + a.z*a.z + a.w*a.w
            + c.x*c.x + c.y*c.y + c.z*c.z + c.w*c.w;
    #pragma unroll
    for (int off = 32; off; off >>= 1) s += __shfl_xor(s, off);
    if (lane == 0) {
        const int b = row >> 11;          // / TT
        const int t = row & (TT - 1);
        unsigned int key = 0u;
        if (t < lengths[b]) key = __float_as_uint(sqrtf(s)) + 1u;
        keys[row] = key;
    }
}

// ---------------------------------------------------------------------------
// Kernel 2: per-row exact top-k selection via binary search on the 43-bit
// composite key ((key<<11) | (2047-t)). All composite keys are distinct, so
// count(>= thr) == k exactly; tie-break matches jax.lax.top_k (lower index
// wins). Selected indices compacted into ws (order irrelevant: sum commutes).
// ---------------------------------------------------------------------------
__global__ __launch_bounds__(256) void topq_select(
    const unsigned int* __restrict__ keys, const int* __restrict__ lengths,
    unsigned short* __restrict__ idx, int* __restrict__ karr,
    float* __restrict__ kf)
{
    __shared__ unsigned int sk[TT];
    __shared__ int sred[4];
    __shared__ int spos;
    const int b   = blockIdx.x;
    const int tid = threadIdx.x;
    for (int i = tid; i < TT; i += 256) sk[i] = keys[b * TT + i];
    if (tid == 0) spos = 0;
    __syncthreads();

    const int len = lengths[b];
    int k = (int)ceilf((float)len * 0.15f);   // fp32 math to bit-match JAX
    if (k < 1) k = 1;

    unsigned long long lo = 0, hi = 1ull << 43;
    while (hi - lo > 1ull) {
        const unsigned long long mid = (lo + hi) >> 1;
        int cnt = 0;
        #pragma unroll
        for (int r = 0; r < TT / 256; ++r) {
            const int i = tid + r * 256;
            const unsigned long long ck =
                ((unsigned long long)sk[i] << 11) | (unsigned long long)(TT - 1 - i);
            cnt += (ck >= mid) ? 1 : 0;
        }
        #pragma unroll
        for (int off = 32; off; off >>= 1) cnt += __shfl_xor(cnt, off);
        if ((tid & 63) == 0) sred[tid >> 6] = cnt;
        __syncthreads();
        const int total = sred[0] + sred[1] + sred[2] + sred[3];
        __syncthreads();
        if (total >= k) lo = mid; else hi = mid;   // block-uniform
    }

    const unsigned long long thr = lo;
    for (int i = tid; i < TT; i += 256) {
        const unsigned long long ck =
            ((unsigned long long)sk[i] << 11) | (unsigned long long)(TT - 1 - i);
        if (ck >= thr) {
            const int p = atomicAdd(&spos, 1);
            idx[b * IDX_STRIDE + p] = (unsigned short)i;
        }
    }
    if (tid == 0) { karr[b] = k; kf[b] = (float)k; }
}

// ---------------------------------------------------------------------------
// Kernel 3: gather-sum. grid (B, 4), 128 threads; thread owns one output
// column. 4-way unrolled over selected indices for load ILP. Reads should be
// L2/L3 hits (H already streamed through cache in kernel 1).
// ---------------------------------------------------------------------------
__global__ __launch_bounds__(128) void topq_pool(
    const float* __restrict__ H, const unsigned short* __restrict__ idx,
    const int* __restrict__ karr, const float* __restrict__ kf,
    float* __restrict__ out)
{
    const int b = blockIdx.x;
    const int c = blockIdx.y * 128 + threadIdx.x;
    const int k = karr[b];
    const unsigned short* mi = idx + b * IDX_STRIDE;
    const float* Hb = H + (size_t)b * TT * DD;
    float a0 = 0.f, a1 = 0.f, a2 = 0.f, a3 = 0.f;
    int j = 0;
    for (; j + 4 <= k; j += 4) {
        const int t0 = mi[j], t1 = mi[j + 1], t2 = mi[j + 2], t3 = mi[j + 3];
        a0 += Hb[(size_t)t0 * DD + c];
        a1 += Hb[(size_t)t1 * DD + c];
        a2 += Hb[(size_t)t2 * DD + c];
        a3 += Hb[(size_t)t3 * DD + c];
    }
    for (; j < k; ++j) a0 += Hb[(size_t)mi[j] * DD + c];
    out[b * DD + c] = ((a0 + a1) + (a2 + a3)) / kf[b];
}

// ---------------------------------------------------------------------------
extern "C" void kernel_launch(void* const* d_in, const int* in_sizes, int n_in,
                              void* d_out, int out_size, void* d_ws, size_t ws_size,
                              hipStream_t stream)
{
    const float* H       = (const float*)d_in[0];
    const int*   lengths = (const int*)d_in[1];
    float*       out     = (float*)d_out;

    char* ws = (char*)d_ws;
    unsigned int*   keys = (unsigned int*)ws;                          // 256 KB
    unsigned short* idx  = (unsigned short*)(ws + (size_t)BB * TT * 4); // 20 KB
    int*   karr = (int*)  (ws + (size_t)BB * TT * 4 + BB * IDX_STRIDE * 2);
    float* kf   = (float*)(ws + (size_t)BB * TT * 4 + BB * IDX_STRIDE * 2 + BB * 4);

    topq_norms <<<dim3(BB * TT / 4), 256, 0, stream>>>(H, lengths, keys);
    topq_select<<<dim3(BB),          256, 0, stream>>>(keys, lengths, idx, karr, kf);
    topq_pool  <<<dim3(BB, 4),       128, 0, stream>>>(H, idx, karr, kf, out);
}

// Round 4
// 215.625 us; speedup vs baseline: 1.1091x; 1.1091x over previous
//
#include <hip/hip_runtime.h>
#include <stdint.h>

static constexpr int BB = 32;
static constexpr int TT = 2048;
static constexpr int DD = 512;
static constexpr int LMAX = 320;   // >= kmax = ceil(2048*0.15) = 308

// ---------------------------------------------------------------------------
// Kernel 1: per-(b,t) L2 norm -> 32-bit order key.
// One wave per timestep row (512 floats = 2KB). key = bits(norm)+1 if valid,
// 0 if t >= len. Non-negative float bits are monotone, +1 keeps valid > masked.
// ---------------------------------------------------------------------------
__global__ __launch_bounds__(256) void topq_norms(
    const float* __restrict__ H, const int* __restrict__ lengths,
    unsigned int* __restrict__ keys)
{
    const int wave = threadIdx.x >> 6;
    const int lane = threadIdx.x & 63;
    const int row  = (blockIdx.x << 2) + wave;          // b*T + t
    const float4* p = reinterpret_cast<const float4*>(H) + (size_t)row * (DD / 4);
    float4 a = p[lane];        // contiguous 1KB per instruction across the wave
    float4 c = p[lane + 64];
    float s = a.x*a.x + a.y*a.y + a.z*a.z + a.w*a.w
            + c.x*c.x + c.y*c.y + c.z*c.z + c.w*c.w;
    #pragma unroll
    for (int off = 32; off; off >>= 1) s += __shfl_xor(s, off);
    if (lane == 0) {
        const int b = row >> 11;          // / TT
        const int t = row & (TT - 1);
        unsigned int key = 0u;
        if (t < lengths[b]) key = __float_as_uint(sqrtf(s)) + 1u;
        keys[row] = key;
    }
}

// ---------------------------------------------------------------------------
// Kernel 2: fused select + pool. One 512-thread block per batch row.
//
// Select (wave 0 only, register-resident, NO barriers): lane holds 32 keys at
// t = j*64+lane (strided -> conflict-free LDS staging reads). Binary search on
// the 43-bit composite ((key<<11)|(2047-t)); all composites distinct, so the
// terminal lo satisfies count(>= lo) == k exactly; tie-break = lower index,
// matching jax.lax.top_k. Selected t's append to an LDS list (order
// irrelevant: sum commutes).
//
// Pool (all 8 waves): thread owns column c = tid; 8 independent accumulators
// give 8 outstanding gather loads per lane to hide L2/L3 latency. Loads are
// block-coalesced (512 threads x 4B = one full 2KB row per step).
// ---------------------------------------------------------------------------
__global__ __launch_bounds__(512) void topq_selpool(
    const unsigned int* __restrict__ keys, const int* __restrict__ lengths,
    const float* __restrict__ H, float* __restrict__ out)
{
    __shared__ unsigned int   sk[TT];      // 8 KB
    __shared__ unsigned short slist[LMAX];
    __shared__ int scount;
    __shared__ int skk;

    const int b   = blockIdx.x;
    const int tid = threadIdx.x;
    for (int i = tid; i < TT; i += 512) sk[i] = keys[b * TT + i];
    if (tid == 0) scount = 0;
    __syncthreads();

    if (tid < 64) {                        // wave 0 does the whole selection
        const int lane = tid;
        unsigned int kreg[32];
        #pragma unroll
        for (int j = 0; j < 32; ++j) kreg[j] = sk[j * 64 + lane];

        const int len = lengths[b];
        int k = (int)ceilf((float)len * 0.15f);   // fp32 math to bit-match JAX
        if (k < 1) k = 1;

        unsigned long long lo = 0, hi = 1ull << 43;
        while (hi - lo > 1ull) {
            const unsigned long long mid = (lo + hi) >> 1;
            int cnt = 0;
            #pragma unroll
            for (int j = 0; j < 32; ++j) {
                const unsigned long long ck =
                    ((unsigned long long)kreg[j] << 11) |
                    (unsigned long long)(TT - 1 - (j * 64 + lane));
                cnt += (ck >= mid) ? 1 : 0;
            }
            #pragma unroll
            for (int off = 32; off; off >>= 1) cnt += __shfl_xor(cnt, off);
            if (cnt >= k) lo = mid; else hi = mid;   // wave-uniform
        }
        #pragma unroll
        for (int j = 0; j < 32; ++j) {
            const unsigned long long ck =
                ((unsigned long long)kreg[j] << 11) |
                (unsigned long long)(TT - 1 - (j * 64 + lane));
            if (ck >= lo) {
                const int p = atomicAdd(&scount, 1);
                slist[p] = (unsigned short)(j * 64 + lane);
            }
        }
        if (tid == 0) skk = k;
    }
    __syncthreads();

    const int k = skk;
    const float* Hb = H + (size_t)b * TT * DD;
    float a0 = 0.f, a1 = 0.f, a2 = 0.f, a3 = 0.f,
          a4 = 0.f, a5 = 0.f, a6 = 0.f, a7 = 0.f;
    int j = 0;
    for (; j + 8 <= k; j += 8) {
        const int t0 = slist[j],     t1 = slist[j + 1],
                  t2 = slist[j + 2], t3 = slist[j + 3],
                  t4 = slist[j + 4], t5 = slist[j + 5],
                  t6 = slist[j + 6], t7 = slist[j + 7];
        a0 += Hb[(size_t)t0 * DD + tid];
        a1 += Hb[(size_t)t1 * DD + tid];
        a2 += Hb[(size_t)t2 * DD + tid];
        a3 += Hb[(size_t)t3 * DD + tid];
        a4 += Hb[(size_t)t4 * DD + tid];
        a5 += Hb[(size_t)t5 * DD + tid];
        a6 += Hb[(size_t)t6 * DD + tid];
        a7 += Hb[(size_t)t7 * DD + tid];
    }
    for (; j < k; ++j) a0 += Hb[(size_t)slist[j] * DD + tid];
    const float s = ((a0 + a1) + (a2 + a3)) + ((a4 + a5) + (a6 + a7));
    out[b * DD + tid] = s / (float)k;
}

// ---------------------------------------------------------------------------
extern "C" void kernel_launch(void* const* d_in, const int* in_sizes, int n_in,
                              void* d_out, int out_size, void* d_ws, size_t ws_size,
                              hipStream_t stream)
{
    const float* H       = (const float*)d_in[0];
    const int*   lengths = (const int*)d_in[1];
    float*       out     = (float*)d_out;

    unsigned int* keys = (unsigned int*)d_ws;    // 256 KB of ws

    topq_norms  <<<dim3(BB * TT / 4), 256, 0, stream>>>(H, lengths, keys);
    topq_selpool<<<dim3(BB),          512, 0, stream>>>(keys, lengths, H, out);
}

// Round 5
// 204.328 us; speedup vs baseline: 1.1704x; 1.0553x over previous
//
#include <hip/hip_runtime.h>
#include <stdint.h>

static constexpr int BB = 32;
static constexpr int TT = 2048;
static constexpr int DD = 512;
static constexpr int LMAX = 320;   // >= kmax = ceil(2048*0.15) = 308

// ---------------------------------------------------------------------------
// Kernel 1: per-(b,t) L2 norm -> 32-bit order key. 4 rows per wave (4
// independent shfl-reduce chains interleave for ILP); lane 0 stores the 4
// consecutive keys as one uint4. key = bits(sqrt(sumsq))+1 if t<len else 0;
// nonneg float bits are monotone, +1 keeps every valid key > every masked key.
// ---------------------------------------------------------------------------
__global__ __launch_bounds__(256) void topq_norms(
    const float* __restrict__ H, const int* __restrict__ lengths,
    unsigned int* __restrict__ keys)
{
    const int wave = threadIdx.x >> 6;
    const int lane = threadIdx.x & 63;
    const int base = (blockIdx.x * 4 + wave) * 4;        // first of 4 rows; 4 | base
    const int b    = base >> 11;                          // rows never cross b (4 | 2048)
    const int len  = lengths[b];
    const float4* p = reinterpret_cast<const float4*>(H) + (size_t)base * (DD / 4);

    float s[4];
    #pragma unroll
    for (int r = 0; r < 4; ++r) {
        float4 a = p[r * (DD / 4) + lane];
        float4 c = p[r * (DD / 4) + lane + 64];
        s[r] = a.x*a.x + a.y*a.y + a.z*a.z + a.w*a.w
             + c.x*c.x + c.y*c.y + c.z*c.z + c.w*c.w;
    }
    #pragma unroll
    for (int off = 32; off; off >>= 1) {
        #pragma unroll
        for (int r = 0; r < 4; ++r) s[r] += __shfl_xor(s[r], off);
    }
    if (lane == 0) {
        const int t0 = base & (TT - 1);
        uint4 kv;
        kv.x = (t0 + 0 < len) ? __float_as_uint(sqrtf(s[0])) + 1u : 0u;
        kv.y = (t0 + 1 < len) ? __float_as_uint(sqrtf(s[1])) + 1u : 0u;
        kv.z = (t0 + 2 < len) ? __float_as_uint(sqrtf(s[2])) + 1u : 0u;
        kv.w = (t0 + 3 < len) ? __float_as_uint(sqrtf(s[3])) + 1u : 0u;
        *reinterpret_cast<uint4*>(keys + base) = kv;
    }
}

// ---------------------------------------------------------------------------
// Kernel 2: fused select + pool, grid (B, 4). Each block selects (redundantly
// across the 4 column-quarter blocks -- parallel CUs, free wall time) and
// pools its 128-column slice.
//
// Select (wave 0, register-resident, barrier-free): binary search for the max
// threshold v with count(key >= v) >= k over [min_valid_key, max_key+1)
// (~22 iterations for concentrated norm keys). Then count(>v)=cgt < k and
// m = k-cgt of the ==v elements are taken in ascending-t order (fast path
// m==ceq needs no ordering; ballot slow path only on exact fp32 norm ties).
// Exactly reproduces jax.lax.top_k's set (ties -> lower index).
//
// Pool: 16 row-groups x 32 float4-column-groups; float4 gathers (each
// half-wave reads a contiguous 512B row segment), LDS tree-reduce, /k exact.
// ---------------------------------------------------------------------------
__global__ __launch_bounds__(512) void topq_selpool(
    const unsigned int* __restrict__ keys, const int* __restrict__ lengths,
    const float* __restrict__ H, float* __restrict__ out)
{
    __shared__ unsigned int   sk[TT];        // 8 KB
    __shared__ unsigned short slist[LMAX];
    __shared__ float4 sred[16][32];          // 8 KB
    __shared__ int scount;
    __shared__ int skk;

    const int b   = blockIdx.x;
    const int q   = blockIdx.y;
    const int tid = threadIdx.x;

    // stage keys: one uint4 per thread
    reinterpret_cast<uint4*>(sk)[tid] =
        reinterpret_cast<const uint4*>(keys + b * TT)[tid];
    if (tid == 0) scount = 0;
    __syncthreads();

    if (tid < 64) {                          // wave 0 does the whole selection
        const int lane = tid;
        unsigned int kreg[32];
        #pragma unroll
        for (int j = 0; j < 32; ++j) kreg[j] = sk[j * 64 + lane];

        const int len = lengths[b];
        int k = (int)ceilf((float)len * 0.15f);   // fp32 math to bit-match JAX
        if (k < 1) k = 1;

        // wave-wide [min valid key, max key]
        unsigned int mn = 0xFFFFFFFFu, mx = 0u;
        #pragma unroll
        for (int j = 0; j < 32; ++j) {
            const unsigned int kk = kreg[j];
            if (kk != 0u && kk < mn) mn = kk;
            if (kk > mx) mx = kk;
        }
        #pragma unroll
        for (int off = 32; off; off >>= 1) {
            const unsigned int mno = (unsigned int)__shfl_xor((int)mn, off);
            const unsigned int mxo = (unsigned int)__shfl_xor((int)mx, off);
            mn = mn < mno ? mn : mno;
            mx = mx > mxo ? mx : mxo;
        }

        // max v with count(key >= v) >= k;  lo=mn: count=len>=k, hi=mx+1: count=0
        unsigned int lo = mn, hi = mx + 1u;
        while (hi - lo > 1u) {
            const unsigned int mid = lo + ((hi - lo) >> 1);
            int cnt = 0;
            #pragma unroll
            for (int j = 0; j < 32; ++j) cnt += (kreg[j] >= mid) ? 1 : 0;
            #pragma unroll
            for (int off = 32; off; off >>= 1) cnt += __shfl_xor(cnt, off);
            if (cnt >= k) lo = mid; else hi = mid;   // wave-uniform
        }
        const unsigned int v = lo;

        int cgt = 0, ceq = 0;
        #pragma unroll
        for (int j = 0; j < 32; ++j) {
            cgt += (kreg[j] > v)  ? 1 : 0;
            ceq += (kreg[j] == v) ? 1 : 0;
        }
        #pragma unroll
        for (int off = 32; off; off >>= 1) {
            cgt += __shfl_xor(cgt, off);
            ceq += __shfl_xor(ceq, off);
        }
        const int m = k - cgt;               // in [1, ceq]

        #pragma unroll
        for (int j = 0; j < 32; ++j) {
            if (kreg[j] > v) {
                const int p = atomicAdd(&scount, 1);
                slist[p] = (unsigned short)(j * 64 + lane);
            }
        }
        if (m == ceq) {                      // common case: take all ==v
            #pragma unroll
            for (int j = 0; j < 32; ++j) {
                if (kreg[j] == v) {
                    const int p = atomicAdd(&scount, 1);
                    slist[p] = (unsigned short)(j * 64 + lane);
                }
            }
        } else {                             // exact ties: first m in t-order
            const unsigned long long ltmask = (1ull << lane) - 1ull;
            int taken = 0;
            for (int c = 0; c < TT / 64 && taken < m; ++c) {
                const int t = c * 64 + lane;
                const bool pred = (sk[t] == v);
                const unsigned long long mask = __ballot(pred);
                const int rank = taken + __popcll(mask & ltmask);
                if (pred && rank < m) {
                    const int p = atomicAdd(&scount, 1);
                    slist[p] = (unsigned short)t;
                }
                taken += __popcll(mask);
            }
        }
        if (lane == 0) skk = k;
    }
    __syncthreads();

    const int k  = skk;
    const int r  = tid >> 5;                 // row group 0..15
    const int cg = tid & 31;                 // float4 column group
    const float4* Hb4 =
        reinterpret_cast<const float4*>(H + (size_t)b * TT * DD);
    const int col4 = q * 32 + cg;

    float4 a0 = {0.f, 0.f, 0.f, 0.f}, a1 = {0.f, 0.f, 0.f, 0.f};
    int j = r;
    for (; j + 16 < k; j += 32) {
        const int t0 = slist[j], t1 = slist[j + 16];
        const float4 x0 = Hb4[(size_t)t0 * 128 + col4];
        const float4 x1 = Hb4[(size_t)t1 * 128 + col4];
        a0.x += x0.x; a0.y += x0.y; a0.z += x0.z; a0.w += x0.w;
        a1.x += x1.x; a1.y += x1.y; a1.z += x1.z; a1.w += x1.w;
    }
    if (j < k) {
        const float4 x0 = Hb4[(size_t)slist[j] * 128 + col4];
        a0.x += x0.x; a0.y += x0.y; a0.z += x0.z; a0.w += x0.w;
    }
    a0.x += a1.x; a0.y += a1.y; a0.z += a1.z; a0.w += a1.w;
    sred[r][cg] = a0;
    __syncthreads();

    if (tid < 32) {
        float4 s = {0.f, 0.f, 0.f, 0.f};
        #pragma unroll
        for (int rr = 0; rr < 16; ++rr) {
            const float4 x = sred[rr][tid];
            s.x += x.x; s.y += x.y; s.z += x.z; s.w += x.w;
        }
        const float kf = (float)k;
        float4 o;
        o.x = s.x / kf; o.y = s.y / kf; o.z = s.z / kf; o.w = s.w / kf;
        reinterpret_cast<float4*>(out)[b * 128 + q * 32 + tid] = o;
    }
}

// ---------------------------------------------------------------------------
extern "C" void kernel_launch(void* const* d_in, const int* in_sizes, int n_in,
                              void* d_out, int out_size, void* d_ws, size_t ws_size,
                              hipStream_t stream)
{
    const float* H       = (const float*)d_in[0];
    const int*   lengths = (const int*)d_in[1];
    float*       out     = (float*)d_out;

    unsigned int* keys = (unsigned int*)d_ws;    // 256 KB of ws

    topq_norms  <<<dim3(BB * TT / 16), 256, 0, stream>>>(H, lengths, keys);
    topq_selpool<<<dim3(BB, 4),        512, 0, stream>>>(keys, lengths, H, out);
}